// Round 3
// baseline (335.271 us; speedup 1.0000x reference)
//
#include <hip/hip_runtime.h>
#include <math.h>

constexpr int M   = 64;       // rows of phi / Y
constexpr int NR  = 256;      // rows of X
constexpr int KK  = NR + M;   // 320: stacked K dim  [W | Z] · [X ; Y]
constexpr int NC  = 131072;   // columns
constexpr int BN  = 32;       // columns per block
constexpr int NT  = BN / 16;  // 2 n-tiles
constexpr int KB  = KK / 32;  // 10 k-blocks of 32
constexpr float THR = 0.1f;

// LDS B layout (bf16, col stride 34): elem(kb,n,kl) at bf16 idx kb*1088 + n*34 + kl
//   as u32 (k-pairs): idx = kb*544 + n*17 + kl/2
//   write bank = (n*17 + kl2) % 32 -> 17 coprime to 32 -> 2-way (free)
//   fragment read = 4 x ds_read_b32 (stride-34 breaks 16B align; read2-pairable)
constexpr int LDS_U32 = KB * 544;     // 5440 u32 = 21760 B

typedef __bf16 bf16x8 __attribute__((ext_vector_type(8)));
typedef float  f32x4  __attribute__((ext_vector_type(4)));

union U4BF8 { uint4 u; bf16x8 v; };

static __device__ __forceinline__ unsigned short f2bf(float f) {
    unsigned int u = __float_as_uint(f);
    u += 0x7FFFu + ((u >> 16) & 1u);        // RNE
    return (unsigned short)(u >> 16);
}

// pack two floats -> bf16 pair (round-half-up: +0x8000 then take high16 via v_perm)
static __device__ __forceinline__ unsigned int pack_rh(float a, float b) {
    unsigned int ua = __float_as_uint(a) + 0x8000u;
    unsigned int ub = __float_as_uint(b) + 0x8000u;
    // result bytes [0,1] = ua bytes [2,3] (low half), [2,3] = ub bytes [2,3]
    return __builtin_amdgcn_perm(ua, ub, 0x03020706u);
}

__global__ __launch_bounds__(256)
void k_copy_phi(const float* __restrict__ phi, float* __restrict__ out)
{
    int i = blockIdx.x * 256 + threadIdx.x;
    out[i] = phi[i];
}

// Build A = [ I - s*phi^T*phi  |  s*phi^T ]  (256 x 320, bf16 row-major) in ws.
__global__ __launch_bounds__(256)
void k_prep(const float* __restrict__ phi, const float* __restrict__ step,
            unsigned short* __restrict__ A)
{
    __shared__ float ph[M * NR];            // 64 KiB
    const int i = blockIdx.x, j = threadIdx.x;
    for (int t = j; t < M * NR; t += 256) ph[t] = phi[t];
    __syncthreads();
    const float s = step[0];
    float d = 0.f;
    #pragma unroll
    for (int m = 0; m < M; ++m)
        d = fmaf(ph[m * NR + i], ph[m * NR + j], d);
    float w = ((i == j) ? 1.f : 0.f) - s * d;
    A[i * KK + j] = f2bf(w);
    if (j < M) A[i * KK + NR + j] = f2bf(s * ph[j * NR + i]);
}

// U = A[256x320] * [X;Y][320xN]; threshold; copy cols >= k.
// 256 thr = 4 waves; wave w owns U rows 64w..64w+63 (4 m-tiles of 16).
__global__ __launch_bounds__(256, 4)
void k_gemm(const unsigned short* __restrict__ A,
            const float* __restrict__ X,
            const float* __restrict__ Y,
            const int*   __restrict__ idxp,
            float* __restrict__ outX)
{
    const int kcols = idxp[0] + 1;
    const int n0    = blockIdx.x * BN;
    const int tid   = threadIdx.x;

    if (n0 >= kcols) {                       // pure-copy fast path
        const int c8 = tid & 7, rg = tid >> 3;
        #pragma unroll
        for (int r = rg; r < NR; r += 32) {
            const float4* src = (const float4*)(X + (size_t)r * NC + n0);
            float4*       dst = (float4*)(outX + (size_t)r * NC + n0);
            dst[c8] = src[c8];
        }
        return;
    }

    const int lane = tid & 63, wave = tid >> 6;
    const int quad = lane >> 4, nlo = lane & 15;
    const int mbase = wave * 64;

    // prefetch A fragments for kb=0 before staging barrier (L2-hot)
    const unsigned short* Ab = A + (size_t)(mbase + nlo) * KK + quad * 8;
    bf16x8 a_cur[4];
    #pragma unroll
    for (int mt = 0; mt < 4; ++mt)
        a_cur[mt] = *(const bf16x8*)(Ab + (size_t)mt * 16 * KK);

    __shared__ unsigned int B[LDS_U32];

    // ---- stage [X;Y] tile -> bf16 LDS (float2 loads, conflict-free writes) ----
    {
        const int ng  = tid & 15;            // cols 2ng, 2ng+1
        const int rp0 = tid >> 4;            // 0..15
        #pragma unroll
        for (int it = 0; it < 10; ++it) {
            const int rp = rp0 + 16 * it;    // row pair 0..159
            const int r  = rp << 1;
            const float* b0 = (r < NR) ? (X + (size_t)r * NC)
                                       : (Y + (size_t)(r - NR) * NC);
            const float* b1 = (r < NR) ? (X + (size_t)(r + 1) * NC)
                                       : (Y + (size_t)(r + 1 - NR) * NC);
            float2 v0 = ((const float2*)(b0 + n0))[ng];
            float2 v1 = ((const float2*)(b1 + n0))[ng];
            const int base = (r >> 5) * 544 + ((r & 31) >> 1);
            B[base + (2 * ng)     * 17] = pack_rh(v0.x, v1.x);
            B[base + (2 * ng + 1) * 17] = pack_rh(v0.y, v1.y);
        }
    }
    __syncthreads();

    f32x4 acc[4][NT];
    #pragma unroll
    for (int mt = 0; mt < 4; ++mt)
        #pragma unroll
        for (int nt = 0; nt < NT; ++nt)
            acc[mt][nt] = (f32x4){0.f, 0.f, 0.f, 0.f};

    const unsigned int* Bb = B + nlo * 17 + quad * 4;

    #pragma unroll
    for (int kb = 0; kb < KB; ++kb) {
        bf16x8 a_nxt[4];
        if (kb < KB - 1) {
            #pragma unroll
            for (int mt = 0; mt < 4; ++mt)
                a_nxt[mt] = *(const bf16x8*)(Ab + (size_t)mt * 16 * KK + (kb + 1) * 32);
        }
        bf16x8 bfr[NT];
        #pragma unroll
        for (int nt = 0; nt < NT; ++nt) {
            const unsigned int* p = Bb + kb * 544 + nt * 272;   // 16*17
            U4BF8 t;
            t.u.x = p[0]; t.u.y = p[1]; t.u.z = p[2]; t.u.w = p[3];
            bfr[nt] = t.v;
        }
        #pragma unroll
        for (int mt = 0; mt < 4; ++mt)
            #pragma unroll
            for (int nt = 0; nt < NT; ++nt)
                acc[mt][nt] = __builtin_amdgcn_mfma_f32_16x16x32_bf16(
                    a_cur[mt], bfr[nt], acc[mt][nt], 0, 0, 0);
        if (kb < KB - 1) {
            #pragma unroll
            for (int mt = 0; mt < 4; ++mt) a_cur[mt] = a_nxt[mt];
        }
    }

    // ---- epilogue: threshold + boundary copy + store ----
    const bool boundary = (n0 + BN > kcols);
    #pragma unroll
    for (int mt = 0; mt < 4; ++mt) {
        #pragma unroll
        for (int nt = 0; nt < NT; ++nt) {
            const int col = n0 + nt * 16 + nlo;
            #pragma unroll
            for (int reg = 0; reg < 4; ++reg) {
                const int row = mbase + mt * 16 + quad * 4 + reg;
                float v = acc[mt][nt][reg];
                v = (fabsf(v) > THR) ? v : 0.f;
                if (boundary && col >= kcols) v = X[(size_t)row * NC + col];
                outX[(size_t)row * NC + col] = v;
            }
        }
    }
}

extern "C" void kernel_launch(void* const* d_in, const int* in_sizes, int n_in,
                              void* d_out, int out_size, void* d_ws, size_t ws_size,
                              hipStream_t stream)
{
    const float* phi  = (const float*)d_in[0];
    const float* X    = (const float*)d_in[1];
    const float* Y    = (const float*)d_in[2];
    const float* step = (const float*)d_in[3];
    const int*   idx  = (const int*)d_in[4];
    float* out = (float*)d_out;
    unsigned short* A = (unsigned short*)d_ws;   // 256*320*2 = 160 KiB

    k_copy_phi<<<(M * NR) / 256, 256, 0, stream>>>(phi, out);
    k_prep<<<NR, 256, 0, stream>>>(phi, step, A);
    k_gemm<<<NC / BN, 256, 0, stream>>>(A, X, Y, idx, out + M * NR);
}